// Round 4
// baseline (280.529 us; speedup 1.0000x reference)
//
#include <hip/hip_runtime.h>
#include <math.h>

#define IN_DIM   128
#define OUT_DIM  128
#define FEAT_DIM 64
#define NB       64     // nodes per k_linear block

// ---------------------------------------------------------------------------
// z = h @ W_fc ; dz = feat @ W_dst.  256 threads/block, 64 nodes/block.
// Thread = (col-group c: 4 cols) x (node-group j0: 8 consecutive nodes).
// LDS holds ONLY the h tile (32 KB), then is re-used for the feat tile
// => 5 blocks/CU. W rows streamed 4-deep per k-step for MLP.
// ---------------------------------------------------------------------------
__global__ __launch_bounds__(256) void k_linear(
        const float* __restrict__ h, const float* __restrict__ feat,
        const float* __restrict__ Wfc, const float* __restrict__ Wdst,
        float* __restrict__ z, float* __restrict__ dz, int N) {
    int t  = threadIdx.x;        // 0..255
    int c  = t & 31;             // cols 4c..4c+3
    int j0 = t >> 5;             // 0..7 -> nodes n0 + 8*j0 + jj
    int n0 = blockIdx.x * NB;

    __shared__ float4 s[NB * 32];   // 32 KB: h tile as [node][32]x16B; reused for feat [node][16]x16B

    // ---- stage h tile (row-clamped) ----
    for (int i = t; i < NB * 32; i += 256) {
        int row = i >> 5, col = i & 31;
        int n = min(n0 + row, N - 1);
        s[i] = ((const float4*)(h + (size_t)n * IN_DIM))[col];
    }
    __syncthreads();

    float4 acc[8];
#pragma unroll
    for (int jj = 0; jj < 8; ++jj) acc[jj] = make_float4(0.f, 0.f, 0.f, 0.f);

    const float4* Wf4 = (const float4*)Wfc;
#pragma unroll 2
    for (int k4 = 0; k4 < IN_DIM / 4; ++k4) {
        float4 w0 = Wf4[(size_t)(4 * k4 + 0) * 32 + c];
        float4 w1 = Wf4[(size_t)(4 * k4 + 1) * 32 + c];
        float4 w2 = Wf4[(size_t)(4 * k4 + 2) * 32 + c];
        float4 w3 = Wf4[(size_t)(4 * k4 + 3) * 32 + c];
#pragma unroll
        for (int jj = 0; jj < 8; ++jj) {
            float4 hv = s[(j0 * 8 + jj) * 32 + k4];
            acc[jj].x += hv.x * w0.x + hv.y * w1.x + hv.z * w2.x + hv.w * w3.x;
            acc[jj].y += hv.x * w0.y + hv.y * w1.y + hv.z * w2.y + hv.w * w3.y;
            acc[jj].z += hv.x * w0.z + hv.y * w1.z + hv.z * w2.z + hv.w * w3.z;
            acc[jj].w += hv.x * w0.w + hv.y * w1.w + hv.z * w2.w + hv.w * w3.w;
        }
    }
#pragma unroll
    for (int jj = 0; jj < 8; ++jj) {
        int n = n0 + j0 * 8 + jj;
        if (n < N) ((float4*)(z + (size_t)n * OUT_DIM))[c] = acc[jj];
    }

    // ---- re-stage LDS with feat tile ----
    __syncthreads();
    for (int i = t; i < NB * 16; i += 256) {
        int row = i >> 4, col = i & 15;
        int n = min(n0 + row, N - 1);
        s[i] = ((const float4*)(feat + (size_t)n * FEAT_DIM))[col];
    }
    __syncthreads();

#pragma unroll
    for (int jj = 0; jj < 8; ++jj) acc[jj] = make_float4(0.f, 0.f, 0.f, 0.f);

    const float4* Wd4 = (const float4*)Wdst;
#pragma unroll 2
    for (int k4 = 0; k4 < FEAT_DIM / 4; ++k4) {
        float4 w0 = Wd4[(size_t)(4 * k4 + 0) * 32 + c];
        float4 w1 = Wd4[(size_t)(4 * k4 + 1) * 32 + c];
        float4 w2 = Wd4[(size_t)(4 * k4 + 2) * 32 + c];
        float4 w3 = Wd4[(size_t)(4 * k4 + 3) * 32 + c];
#pragma unroll
        for (int jj = 0; jj < 8; ++jj) {
            float4 fv = s[(j0 * 8 + jj) * 16 + k4];
            acc[jj].x += fv.x * w0.x + fv.y * w1.x + fv.z * w2.x + fv.w * w3.x;
            acc[jj].y += fv.x * w0.y + fv.y * w1.y + fv.z * w2.y + fv.w * w3.y;
            acc[jj].z += fv.x * w0.z + fv.y * w1.z + fv.z * w2.z + fv.w * w3.z;
            acc[jj].w += fv.x * w0.w + fv.y * w1.w + fv.z * w2.w + fv.w * w3.w;
        }
    }
#pragma unroll
    for (int jj = 0; jj < 8; ++jj) {
        int n = n0 + j0 * 8 + jj;
        if (n < N) ((float4*)(dz + (size_t)n * OUT_DIM))[c] = acc[jj];
    }
}

// ---------------------------------------------------------------------------
// CSR build: histogram by dst -> exclusive scan -> scatter SRC NODE IDS
// ---------------------------------------------------------------------------
__global__ void k_hist(const int* __restrict__ dst, unsigned* __restrict__ counts, int E) {
    for (int i = blockIdx.x * blockDim.x + threadIdx.x; i < E; i += gridDim.x * blockDim.x)
        atomicAdd(&counts[dst[i]], 1u);
}

__global__ void k_scan(const unsigned* __restrict__ counts, unsigned* __restrict__ offsets, int N) {
    __shared__ unsigned s[1024];
    int t = threadIdx.x;
    int per = (N + 1023) / 1024;
    int b = t * per;
    int e_ = min(N, b + per);
    unsigned sum = 0;
    for (int i = b; i < e_; ++i) sum += counts[i];
    s[t] = sum;
    __syncthreads();
    for (int off = 1; off < 1024; off <<= 1) {
        unsigned v = (t >= off) ? s[t - off] : 0u;
        __syncthreads();
        s[t] += v;
        __syncthreads();
    }
    unsigned run = s[t] - sum;
    for (int i = b; i < e_; ++i) { offsets[i] = run; run += counts[i]; }
    if (t == 1023) offsets[N] = s[1023];
}

__global__ void k_scatter(const int* __restrict__ dst, const int* __restrict__ src,
                          const unsigned* __restrict__ offsets,
                          unsigned* __restrict__ cursor, unsigned* __restrict__ csr, int E) {
    for (int i = blockIdx.x * blockDim.x + threadIdx.x; i < E; i += gridDim.x * blockDim.x) {
        int d = dst[i];
        unsigned pos = offsets[d] + atomicAdd(&cursor[d], 1u);
        csr[pos] = (unsigned)src[i];   // payload = source node id
    }
}

// ---------------------------------------------------------------------------
// Fused attention + aggregation. One 128-thread block per node, 4 groups of
// 32 lanes; each group unrolls 4 edges deep (16 z-rows in flight per block).
//   out[n] = sum_e exp(<z[s_e], dz[n]>) * z[s_e]  /  sum_e exp(...)
// ---------------------------------------------------------------------------
__device__ __forceinline__ float dot4(float4 a, float4 b) {
    return a.x * b.x + a.y * b.y + a.z * b.z + a.w * b.w;
}
__device__ __forceinline__ float red32(float p) {
#pragma unroll
    for (int off = 16; off; off >>= 1) p += __shfl_xor(p, off);
    return p;
}

__global__ __launch_bounds__(128) void k_node(
        const float* __restrict__ z, const float* __restrict__ dz,
        const unsigned* __restrict__ offsets, const unsigned* __restrict__ csr,
        float* __restrict__ out, int N) {
    int n = blockIdx.x, t = threadIdx.x;
    int lane = t & 31, g = t >> 5;       // 4 groups of 32 lanes
    unsigned start = offsets[n];
    int deg = (int)(offsets[n + 1] - start);
    if (deg == 0) { out[(size_t)n * OUT_DIM + t] = 0.f; return; }

    float4 dzv = ((const float4*)(dz + (size_t)n * OUT_DIM))[lane];

    float4 acc = make_float4(0.f, 0.f, 0.f, 0.f);
    float denom = 0.f;

    int i = g;
    for (; i + 12 < deg; i += 16) {      // 4 edges in flight per group
        int s0 = (int)csr[start + i];
        int s1 = (int)csr[start + i + 4];
        int s2 = (int)csr[start + i + 8];
        int s3 = (int)csr[start + i + 12];
        float4 z0 = ((const float4*)(z + (size_t)s0 * OUT_DIM))[lane];
        float4 z1 = ((const float4*)(z + (size_t)s1 * OUT_DIM))[lane];
        float4 z2 = ((const float4*)(z + (size_t)s2 * OUT_DIM))[lane];
        float4 z3 = ((const float4*)(z + (size_t)s3 * OUT_DIM))[lane];
        float p0 = red32(dot4(z0, dzv));
        float p1 = red32(dot4(z1, dzv));
        float p2 = red32(dot4(z2, dzv));
        float p3 = red32(dot4(z3, dzv));
        float w0 = __expf(p0), w1 = __expf(p1), w2 = __expf(p2), w3 = __expf(p3);
        denom += (w0 + w1) + (w2 + w3);
        acc.x += w0 * z0.x + w1 * z1.x + w2 * z2.x + w3 * z3.x;
        acc.y += w0 * z0.y + w1 * z1.y + w2 * z2.y + w3 * z3.y;
        acc.z += w0 * z0.z + w1 * z1.z + w2 * z2.z + w3 * z3.z;
        acc.w += w0 * z0.w + w1 * z1.w + w2 * z2.w + w3 * z3.w;
    }
    for (; i < deg; i += 4) {            // remainder
        int s0 = (int)csr[start + i];
        float4 z0 = ((const float4*)(z + (size_t)s0 * OUT_DIM))[lane];
        float w0 = __expf(red32(dot4(z0, dzv)));
        denom += w0;
        acc.x += w0 * z0.x; acc.y += w0 * z0.y;
        acc.z += w0 * z0.z; acc.w += w0 * z0.w;
    }

    __shared__ float s_acc[4][OUT_DIM];
    __shared__ float s_den[4];
    ((float4*)&s_acc[g][0])[lane] = acc;
    if (lane == 0) s_den[g] = denom;
    __syncthreads();
    float r = (s_acc[0][t] + s_acc[1][t]) + (s_acc[2][t] + s_acc[3][t]);
    float d = (s_den[0] + s_den[1]) + (s_den[2] + s_den[3]);
    out[(size_t)n * OUT_DIM + t] = r / d;
}

// ---------------------------------------------------------------------------
extern "C" void kernel_launch(void* const* d_in, const int* in_sizes, int n_in,
                              void* d_out, int out_size, void* d_ws, size_t ws_size,
                              hipStream_t stream) {
    const float* h    = (const float*)d_in[0];
    const float* feat = (const float*)d_in[1];
    const float* Wfc  = (const float*)d_in[2];
    const float* Wdst = (const float*)d_in[3];
    const int*   src  = (const int*)d_in[4];
    const int*   dst  = (const int*)d_in[5];
    float*       out  = (float*)d_out;

    int N = in_sizes[0] / IN_DIM;
    int E = in_sizes[4];

    char* ws = (char*)d_ws;
    float*    z       = (float*)ws;    ws += (size_t)N * OUT_DIM * sizeof(float);
    float*    dz      = (float*)ws;    ws += (size_t)N * OUT_DIM * sizeof(float);
    unsigned* counts  = (unsigned*)ws; ws += (size_t)N * sizeof(unsigned);
    unsigned* cursor  = (unsigned*)ws; ws += (size_t)N * sizeof(unsigned);
    unsigned* offsets = (unsigned*)ws; ws += (size_t)(N + 1) * sizeof(unsigned);
    unsigned* csr     = (unsigned*)ws;

    hipMemsetAsync(counts, 0, (size_t)2 * N * sizeof(unsigned), stream);

    k_linear <<<(N + NB - 1) / NB, 256, 0, stream>>>(h, feat, Wfc, Wdst, z, dz, N);
    k_hist   <<<1024, 256, 0, stream>>>(dst, counts, E);
    k_scan   <<<1, 1024, 0, stream>>>(counts, offsets, N);
    k_scatter<<<1024, 256, 0, stream>>>(dst, src, offsets, cursor, csr, E);
    k_node   <<<N, 128, 0, stream>>>(z, dz, offsets, csr, out, N);
}

// Round 5
// 205.939 us; speedup vs baseline: 1.3622x; 1.3622x over previous
//
#include <hip/hip_runtime.h>
#include <math.h>

#define IN_DIM   128
#define OUT_DIM  128
#define FEAT_DIM 64
#define NB       64     // nodes per k_linear block
#define SCH      256    // scan chunk size

// ---------------------------------------------------------------------------
// z = h @ W_fc ; dz = feat @ W_dst.  256 threads/block, 64 nodes/block.
// Thread = (col-group c: 4 cols) x (node-group j0: 8 consecutive nodes).
// LDS holds ONLY the h tile (32 KB), reused for feat => 5 blocks/CU.
// ---------------------------------------------------------------------------
__global__ __launch_bounds__(256) void k_linear(
        const float* __restrict__ h, const float* __restrict__ feat,
        const float* __restrict__ Wfc, const float* __restrict__ Wdst,
        float* __restrict__ z, float* __restrict__ dz, int N) {
    int t  = threadIdx.x;        // 0..255
    int c  = t & 31;             // cols 4c..4c+3
    int j0 = t >> 5;             // 0..7 -> nodes n0 + 8*j0 + jj
    int n0 = blockIdx.x * NB;

    __shared__ float4 s[NB * 32];   // 32 KB

    for (int i = t; i < NB * 32; i += 256) {
        int row = i >> 5, col = i & 31;
        int n = min(n0 + row, N - 1);
        s[i] = ((const float4*)(h + (size_t)n * IN_DIM))[col];
    }
    __syncthreads();

    float4 acc[8];
#pragma unroll
    for (int jj = 0; jj < 8; ++jj) acc[jj] = make_float4(0.f, 0.f, 0.f, 0.f);

    const float4* Wf4 = (const float4*)Wfc;
#pragma unroll 2
    for (int k4 = 0; k4 < IN_DIM / 4; ++k4) {
        float4 w0 = Wf4[(size_t)(4 * k4 + 0) * 32 + c];
        float4 w1 = Wf4[(size_t)(4 * k4 + 1) * 32 + c];
        float4 w2 = Wf4[(size_t)(4 * k4 + 2) * 32 + c];
        float4 w3 = Wf4[(size_t)(4 * k4 + 3) * 32 + c];
#pragma unroll
        for (int jj = 0; jj < 8; ++jj) {
            float4 hv = s[(j0 * 8 + jj) * 32 + k4];
            acc[jj].x += hv.x * w0.x + hv.y * w1.x + hv.z * w2.x + hv.w * w3.x;
            acc[jj].y += hv.x * w0.y + hv.y * w1.y + hv.z * w2.y + hv.w * w3.y;
            acc[jj].z += hv.x * w0.z + hv.y * w1.z + hv.z * w2.z + hv.w * w3.z;
            acc[jj].w += hv.x * w0.w + hv.y * w1.w + hv.z * w2.w + hv.w * w3.w;
        }
    }
#pragma unroll
    for (int jj = 0; jj < 8; ++jj) {
        int n = n0 + j0 * 8 + jj;
        if (n < N) ((float4*)(z + (size_t)n * OUT_DIM))[c] = acc[jj];
    }

    __syncthreads();
    for (int i = t; i < NB * 16; i += 256) {
        int row = i >> 4, col = i & 15;
        int n = min(n0 + row, N - 1);
        s[i] = ((const float4*)(feat + (size_t)n * FEAT_DIM))[col];
    }
    __syncthreads();

#pragma unroll
    for (int jj = 0; jj < 8; ++jj) acc[jj] = make_float4(0.f, 0.f, 0.f, 0.f);

    const float4* Wd4 = (const float4*)Wdst;
#pragma unroll 2
    for (int k4 = 0; k4 < FEAT_DIM / 4; ++k4) {
        float4 w0 = Wd4[(size_t)(4 * k4 + 0) * 32 + c];
        float4 w1 = Wd4[(size_t)(4 * k4 + 1) * 32 + c];
        float4 w2 = Wd4[(size_t)(4 * k4 + 2) * 32 + c];
        float4 w3 = Wd4[(size_t)(4 * k4 + 3) * 32 + c];
#pragma unroll
        for (int jj = 0; jj < 8; ++jj) {
            float4 fv = s[(j0 * 8 + jj) * 16 + k4];
            acc[jj].x += fv.x * w0.x + fv.y * w1.x + fv.z * w2.x + fv.w * w3.x;
            acc[jj].y += fv.x * w0.y + fv.y * w1.y + fv.z * w2.y + fv.w * w3.y;
            acc[jj].z += fv.x * w0.z + fv.y * w1.z + fv.z * w2.z + fv.w * w3.z;
            acc[jj].w += fv.x * w0.w + fv.y * w1.w + fv.z * w2.w + fv.w * w3.w;
        }
    }
#pragma unroll
    for (int jj = 0; jj < 8; ++jj) {
        int n = n0 + j0 * 8 + jj;
        if (n < N) ((float4*)(dz + (size_t)n * OUT_DIM))[c] = acc[jj];
    }
}

// ---------------------------------------------------------------------------
// CSR build: histogram -> device-wide exclusive scan (3 kernels) -> scatter
// ---------------------------------------------------------------------------
__global__ void k_hist(const int* __restrict__ dst, unsigned* __restrict__ counts, int E) {
    for (int i = blockIdx.x * blockDim.x + threadIdx.x; i < E; i += gridDim.x * blockDim.x)
        atomicAdd(&counts[dst[i]], 1u);
}

// stage 1: per-block (chunk of SCH) reduce -> partials[b]
__global__ __launch_bounds__(SCH) void k_scan1(const unsigned* __restrict__ counts,
                                               unsigned* __restrict__ partials, int N) {
    int b = blockIdx.x, t = threadIdx.x;
    int idx = b * SCH + t;
    unsigned v = (idx < N) ? counts[idx] : 0u;
#pragma unroll
    for (int off = 32; off; off >>= 1) v += __shfl_xor(v, off);   // wave64 reduce
    __shared__ unsigned sw[SCH / 64];
    if ((t & 63) == 0) sw[t >> 6] = v;
    __syncthreads();
    if (t == 0) {
        unsigned s = 0;
#pragma unroll
        for (int i = 0; i < SCH / 64; ++i) s += sw[i];
        partials[b] = s;
    }
}

// stage 2: exclusive scan of partials (single small block; nblk <= 1024)
__global__ __launch_bounds__(1024) void k_scan2(unsigned* __restrict__ partials, int nblk) {
    __shared__ unsigned s[1024];
    int t = threadIdx.x;
    unsigned v = (t < nblk) ? partials[t] : 0u;
    s[t] = v;
    __syncthreads();
    for (int off = 1; off < 1024; off <<= 1) {
        unsigned u = (t >= off) ? s[t - off] : 0u;
        __syncthreads();
        s[t] += u;
        __syncthreads();
    }
    if (t < nblk) partials[t] = s[t] - v;   // exclusive base per block
}

// stage 3: block-local scan + base -> offsets[0..N]
__global__ __launch_bounds__(SCH) void k_scan3(const unsigned* __restrict__ counts,
                                               const unsigned* __restrict__ partials,
                                               unsigned* __restrict__ offsets, int N) {
    int b = blockIdx.x, t = threadIdx.x;
    int idx = b * SCH + t;
    unsigned v = (idx < N) ? counts[idx] : 0u;
    __shared__ unsigned s[SCH];
    s[t] = v;
    __syncthreads();
    for (int off = 1; off < SCH; off <<= 1) {
        unsigned u = (t >= off) ? s[t - off] : 0u;
        __syncthreads();
        s[t] += u;
        __syncthreads();
    }
    unsigned base = partials[b];
    if (idx < N)  offsets[idx] = base + s[t] - v;
    if (idx == N - 1) offsets[N] = base + s[t];
}

__global__ void k_scatter(const int* __restrict__ dst, const int* __restrict__ src,
                          const unsigned* __restrict__ offsets,
                          unsigned* __restrict__ cursor, unsigned* __restrict__ csr, int E) {
    for (int i = blockIdx.x * blockDim.x + threadIdx.x; i < E; i += gridDim.x * blockDim.x) {
        int d = dst[i];
        unsigned pos = offsets[d] + atomicAdd(&cursor[d], 1u);
        csr[pos] = (unsigned)src[i];   // payload = source node id
    }
}

// ---------------------------------------------------------------------------
// Fused attention + aggregation. One 128-thread block per node, 4 groups of
// 32 lanes; each group unrolls 4 edges deep (16 z-rows in flight per block).
// ---------------------------------------------------------------------------
__device__ __forceinline__ float dot4(float4 a, float4 b) {
    return a.x * b.x + a.y * b.y + a.z * b.z + a.w * b.w;
}
__device__ __forceinline__ float red32(float p) {
#pragma unroll
    for (int off = 16; off; off >>= 1) p += __shfl_xor(p, off);
    return p;
}

__global__ __launch_bounds__(128) void k_node(
        const float* __restrict__ z, const float* __restrict__ dz,
        const unsigned* __restrict__ offsets, const unsigned* __restrict__ csr,
        float* __restrict__ out, int N) {
    int n = blockIdx.x, t = threadIdx.x;
    int lane = t & 31, g = t >> 5;       // 4 groups of 32 lanes
    unsigned start = offsets[n];
    int deg = (int)(offsets[n + 1] - start);
    if (deg == 0) { out[(size_t)n * OUT_DIM + t] = 0.f; return; }

    float4 dzv = ((const float4*)(dz + (size_t)n * OUT_DIM))[lane];

    float4 acc = make_float4(0.f, 0.f, 0.f, 0.f);
    float denom = 0.f;

    int i = g;
    for (; i + 12 < deg; i += 16) {      // 4 edges in flight per group
        int s0 = (int)csr[start + i];
        int s1 = (int)csr[start + i + 4];
        int s2 = (int)csr[start + i + 8];
        int s3 = (int)csr[start + i + 12];
        float4 z0 = ((const float4*)(z + (size_t)s0 * OUT_DIM))[lane];
        float4 z1 = ((const float4*)(z + (size_t)s1 * OUT_DIM))[lane];
        float4 z2 = ((const float4*)(z + (size_t)s2 * OUT_DIM))[lane];
        float4 z3 = ((const float4*)(z + (size_t)s3 * OUT_DIM))[lane];
        float p0 = red32(dot4(z0, dzv));
        float p1 = red32(dot4(z1, dzv));
        float p2 = red32(dot4(z2, dzv));
        float p3 = red32(dot4(z3, dzv));
        float w0 = __expf(p0), w1 = __expf(p1), w2 = __expf(p2), w3 = __expf(p3);
        denom += (w0 + w1) + (w2 + w3);
        acc.x += w0 * z0.x + w1 * z1.x + w2 * z2.x + w3 * z3.x;
        acc.y += w0 * z0.y + w1 * z1.y + w2 * z2.y + w3 * z3.y;
        acc.z += w0 * z0.z + w1 * z1.z + w2 * z2.z + w3 * z3.z;
        acc.w += w0 * z0.w + w1 * z1.w + w2 * z2.w + w3 * z3.w;
    }
    for (; i < deg; i += 4) {            // remainder
        int s0 = (int)csr[start + i];
        float4 z0 = ((const float4*)(z + (size_t)s0 * OUT_DIM))[lane];
        float w0 = __expf(red32(dot4(z0, dzv)));
        denom += w0;
        acc.x += w0 * z0.x; acc.y += w0 * z0.y;
        acc.z += w0 * z0.z; acc.w += w0 * z0.w;
    }

    __shared__ float s_acc[4][OUT_DIM];
    __shared__ float s_den[4];
    ((float4*)&s_acc[g][0])[lane] = acc;
    if (lane == 0) s_den[g] = denom;
    __syncthreads();
    float r = (s_acc[0][t] + s_acc[1][t]) + (s_acc[2][t] + s_acc[3][t]);
    float d = (s_den[0] + s_den[1]) + (s_den[2] + s_den[3]);
    out[(size_t)n * OUT_DIM + t] = r / d;
}

// ---------------------------------------------------------------------------
extern "C" void kernel_launch(void* const* d_in, const int* in_sizes, int n_in,
                              void* d_out, int out_size, void* d_ws, size_t ws_size,
                              hipStream_t stream) {
    const float* h    = (const float*)d_in[0];
    const float* feat = (const float*)d_in[1];
    const float* Wfc  = (const float*)d_in[2];
    const float* Wdst = (const float*)d_in[3];
    const int*   src  = (const int*)d_in[4];
    const int*   dst  = (const int*)d_in[5];
    float*       out  = (float*)d_out;

    int N = in_sizes[0] / IN_DIM;
    int E = in_sizes[4];

    char* ws = (char*)d_ws;
    float*    z        = (float*)ws;    ws += (size_t)N * OUT_DIM * sizeof(float);
    float*    dz       = (float*)ws;    ws += (size_t)N * OUT_DIM * sizeof(float);
    unsigned* counts   = (unsigned*)ws; ws += (size_t)N * sizeof(unsigned);
    unsigned* cursor   = (unsigned*)ws; ws += (size_t)N * sizeof(unsigned);
    unsigned* offsets  = (unsigned*)ws; ws += (size_t)(N + 1) * sizeof(unsigned);
    unsigned* partials = (unsigned*)ws; ws += (size_t)1024 * sizeof(unsigned);
    unsigned* csr      = (unsigned*)ws;

    int nblk = (N + SCH - 1) / SCH;     // 196 for N=50000 (<=1024 supported)

    hipMemsetAsync(counts, 0, (size_t)2 * N * sizeof(unsigned), stream);

    k_linear <<<(N + NB - 1) / NB, 256, 0, stream>>>(h, feat, Wfc, Wdst, z, dz, N);
    k_hist   <<<1024, 256, 0, stream>>>(dst, counts, E);
    k_scan1  <<<nblk, SCH, 0, stream>>>(counts, partials, N);
    k_scan2  <<<1, 1024, 0, stream>>>(partials, nblk);
    k_scan3  <<<nblk, SCH, 0, stream>>>(counts, partials, offsets, N);
    k_scatter<<<1024, 256, 0, stream>>>(dst, src, offsets, cursor, csr, E);
    k_node   <<<N, 128, 0, stream>>>(z, dz, offsets, csr, out, N);
}